// Round 13
// baseline (152.239 us; speedup 1.0000x reference)
//
#include <hip/hip_runtime.h>
#include <math.h>

#define Hd 128
#define Wd 128
#define HW 16384      // 128*128
#define EPSc 1e-6f

typedef __attribute__((ext_vector_type(8))) short s8v;    // 8 bf16 (4 VGPRs)
typedef __attribute__((ext_vector_type(4))) float f4v;    // 4 fp32

__device__ __forceinline__ unsigned short f2bf(float f) {
    unsigned int u = __float_as_uint(f);
    unsigned int r = (u + 0x7FFFu + ((u >> 16) & 1u)) >> 16;   // RNE
    return (unsigned short)r;
}

__device__ __forceinline__ float rcpf(float x) { return __builtin_amdgcn_rcpf(x); }

// fast atan2, max err ~1e-5 rad (A&S 4.4.49 deg-9 on [0,1] + quadrant fixup)
__device__ __forceinline__ float fatan2(float sy, float sx) {
    float ax = fabsf(sx), ay = fabsf(sy);
    float mx = fmaxf(ax, ay), mn = fminf(ax, ay);
    float q = mn * rcpf(mx);
    float s = q * q;
    float r = q * fmaf(s, fmaf(s, fmaf(s, fmaf(s, 0.0208351f, -0.0851330f),
                                       0.1801410f), -0.3302995f), 0.9998660f);
    if (ay > ax) r = 1.5707963268f - r;
    if (sx < 0.f) r = 3.14159265359f - r;
    r = (sy < 0.f) ? -r : r;
    return (mx == 0.f) ? 0.f : r;
}

// ---------------------------------------------------------------------------
// K_A: 3 roles by blockIdx.x.
//  [0,2048):    sobcons — sobel + 5x5 weighted circular-variance; writes
//               gx/gy as bf16 NHWC[p][128] and NON-ATOMIC per-quadrant
//               channel-mean partials cmPart[b*16+q][px].
//               Cons phase uses the 3-box-sum identity
//               sum((d-w)^2 m) = sum(d^2 m) - 2w sum(dm) + w^2 sum(m),
//               w = sum(dm)/(sum(m)+eps): ONE LDS pass, no register arrays
//               (r4-r12 kept mv[25]/dv[25] under a 64-VGPR cap -> double
//               LDS reads / spill pressure).
//  [2048,2560): x NCHW fp32 -> xh NHWC bf16 (16 ch/thread).
//  [2560,2893): weight prep (bf16 casts / transposes).
__global__ __launch_bounds__(256, 8)
void k_A(const float* __restrict__ x,
         const float* __restrict__ wgx, const float* __restrict__ wgy,
         const float* __restrict__ ga_w1, const float* __restrict__ ga_w2,
         const float* __restrict__ cd_w1,
         const float* __restrict__ ec_w1, const float* __restrict__ ec_w2,
         unsigned short* __restrict__ gxgyh, float* __restrict__ cmPart,
         unsigned short* __restrict__ xh,
         unsigned short* __restrict__ w1m, unsigned short* __restrict__ w2m,
         float* __restrict__ cd_w1t,
         unsigned short* __restrict__ w1h, unsigned short* __restrict__ w2h) {
    __shared__ float xt[484];        // 22x22 x-tile (3-halo)
    __shared__ float lm[480];        // 20 rows x stride 24
    __shared__ float ld[480];
    int bid = blockIdx.x;
    int tid = threadIdx.x;

    if (bid < 2048) {                // ---------------- sobcons role
        int bx = bid & 7, by = (bid >> 3) & 7, z = bid >> 6;
        int tx = tid & 15, ty = tid >> 4;
        int x0 = bx * 16, y0 = by * 16;
        int b = z >> 4, cb = (z & 15) * 4;
        float acc = 0.f;
        for (int c = 0; c < 4; c++) {
            int ch = cb + c;
            const float* xp = x + (size_t)(b * 64 + ch) * HW;
            float wx[9], wy[9];
#pragma unroll
            for (int i = 0; i < 9; i++) { wx[i] = wgx[ch * 9 + i]; wy[i] = wgy[ch * 9 + i]; }
            __syncthreads();    // previous channel's cons reads done
            for (int i = tid; i < 484; i += 256) {
                int yy = i / 22, xx = i - yy * 22;
                int gyy = y0 - 3 + yy, gxx = x0 - 3 + xx;
                xt[i] = (gyy >= 0 && gyy < Hd && gxx >= 0 && gxx < Wd) ? xp[gyy * Wd + gxx] : 0.f;
            }
            __syncthreads();
            for (int i = tid; i < 400; i += 256) {
                int yy = i / 20, xx = i - yy * 20;
                int gyy = y0 - 2 + yy, gxx = x0 - 2 + xx;
                float m = 0.f, d = 0.f, sx = 0.f, sy = 0.f;
                if (gyy >= 0 && gyy < Hd && gxx >= 0 && gxx < Wd) {
#pragma unroll
                    for (int dy = 0; dy < 3; dy++)
#pragma unroll
                        for (int dx = 0; dx < 3; dx++) {
                            float v = xt[(yy + dy) * 22 + xx + dx];
                            sx = fmaf(wx[dy * 3 + dx], v, sx);
                            sy = fmaf(wy[dy * 3 + dx], v, sy);
                        }
                    m = sqrtf(sx * sx + sy * sy + EPSc);
                    d = fatan2(sy, sx);
                }
                lm[yy * 24 + xx] = m;
                ld[yy * 24 + xx] = d;
                if (yy >= 2 && yy < 18 && xx >= 2 && xx < 18) {
                    size_t pb = ((size_t)b * HW + gyy * Wd + gxx) * 128;
                    gxgyh[pb + ch] = f2bf(sx);
                    gxgyh[pb + 64 + ch] = f2bf(sy);
                }
            }
            __syncthreads();
            float sm = 0.f, sdm = 0.f, sd2m = 0.f;
#pragma unroll
            for (int r = 0; r < 5; r++)
#pragma unroll
                for (int cx = 0; cx < 5; cx++) {
                    int idx = (ty + r) * 24 + tx + cx;
                    float m = lm[idx], d = ld[idx];
                    sm += m;
                    float dm = d * m;
                    sdm += dm;
                    sd2m = fmaf(d, dm, sd2m);
                }
            float rinv = rcpf(sm + EPSc);
            float w = sdm * rinv;
            float sv = fmaf(w, fmaf(w, sm, -2.f * sdm), sd2m);  // sd2m - 2w*sdm + w^2*sm
            sv = fmaxf(sv, 0.f);
            float wstd = sqrtf(sv * rinv);
            acc += 2.f * rcpf(__expf(2.f * wstd) + 1.f);   // = 1 - tanh(wstd)
        }
        cmPart[(size_t)z * HW + (y0 + ty) * Wd + x0 + tx] = acc * (1.f / 64.f);
        return;
    }
    if (bid < 2560) {                // ---------------- xh role (16 ch/thread)
        int idx = (bid - 2048) * 256 + tid;    // [0, 131072)
        int cg = idx >> 15;                    // 16-ch group 0..3
        int p  = idx & 32767;
        int b = p >> 14, s = p & (HW - 1);
        const float* xp = x + ((size_t)b * 64 + cg * 16) * HW + s;
        alignas(16) unsigned short buf[16];
#pragma unroll
        for (int k = 0; k < 16; k++) buf[k] = f2bf(xp[k * HW]);
        uint4* dst = (uint4*)(xh + (size_t)p * 64 + cg * 16);
        dst[0] = ((const uint4*)buf)[0];
        dst[1] = ((const uint4*)buf)[1];
        return;
    }
    int i = (bid - 2560) * 256 + tid;          // ------- weight prep
    if (i < 36864) {                               // w1h [t][co][ci] bf16 (ec_w1)
        int t = i >> 12, co = (i >> 6) & 63, ci = i & 63;
        w1h[i] = f2bf(ec_w1[(co * 64 + ci) * 9 + t]);
    } else if (i < 73728) {                        // w2h (ec_w2)
        int j = i - 36864;
        int t = j >> 12, co = (j >> 6) & 63, ci = j & 63;
        w2h[j] = f2bf(ec_w2[(co * 64 + ci) * 9 + t]);
    } else if (i < 81920) {                        // w1m [co64][K128] = ga_w1 cast
        int j = i - 73728;
        w1m[j] = f2bf(ga_w1[j]);
    } else if (i < 82944) {                        // w2m [co16][ci64] = ga_w2 cast
        int j = i - 81920;
        w2m[j] = f2bf(ga_w2[j]);
    } else if (i < 85248) {                        // cd_w1t [ci16][tap9][co16] fp32
        int j = i - 82944;
        int co = j & 15, r = j >> 4, t = r % 9, ci = r / 9;
        cd_w1t[j] = cd_w1[(co * 16 + ci) * 9 + t];
    }
}

// ---------------------------------------------------------------------------
// K_B: 2 roles by blockIdx.x (LDS union 24 KB).
//  [0,512):    conv64 stage-1 (3x3 64->64 MFMA, relu -> bf16 NHWC ee1h)
//  [512,1024): gam — ga1+ga2 fused MFMA GEMM -> ga2 fp32 NCHW
__global__ __launch_bounds__(256, 2)
void k_B(const unsigned short* __restrict__ xh,
         const unsigned short* __restrict__ w1h, const float* __restrict__ ec_b1,
         unsigned short* __restrict__ ee1h,
         const unsigned short* __restrict__ gxgyh,
         const unsigned short* __restrict__ w1m, const float* __restrict__ b1,
         const unsigned short* __restrict__ w2m, const float* __restrict__ b2,
         float* __restrict__ ga2) {
    __shared__ unsigned short shb[12288];   // 24 KB union
    int bid = blockIdx.x;
    int tid = threadIdx.x;
    int lane = tid & 63, wv = tid >> 6;
    int l15 = lane & 15, lq = lane >> 4;

    if (bid < 512) {                 // ---------------- conv64 stage-1 role
        unsigned short* tile = shb;  // 100x64 bf16, 12.8 KB
        int j = bid;
        int x0 = (j & 15) * 8, y0 = ((j >> 4) & 15) * 8;
        int b = j >> 8;
        const size_t ibase = (size_t)b * HW * 64;

        for (int i = tid; i < 800; i += 256) {
            int py = i / 80;
            int r = i - py * 80;
            int px = r >> 3, cg = r & 7;
            int gy = y0 - 1 + py, gx = x0 - 1 + px;
            uint4 v = {0u, 0u, 0u, 0u};
            if (gy >= 0 && gy < Hd && gx >= 0 && gx < Wd)
                v = *(const uint4*)(xh + ibase + (size_t)(gy * Wd + gx) * 64 + cg * 8);
            int rowlin = py * 10 + px;
            int scg = cg ^ (rowlin & 7);
            *(uint4*)(tile + rowlin * 64 + scg * 8) = v;
        }
        int co_base = wv * 16;
        s8v af[9][2];
#pragma unroll
        for (int t = 0; t < 9; t++)
#pragma unroll
            for (int h = 0; h < 2; h++)
                af[t][h] = *(const s8v*)(w1h + ((t * 64 + co_base + l15) * 64 + h * 32 + lq * 8));
        f4v bv = *(const f4v*)(ec_b1 + co_base + lq * 4);
        f4v acc[4];
#pragma unroll
        for (int n = 0; n < 4; n++) acc[n] = bv;
        __syncthreads();
#pragma unroll
        for (int n = 0; n < 4; n++) {
            int px = n * 16 + l15;
            int pyy = px >> 3, pxx = px & 7;
#pragma unroll
            for (int dy = 0; dy < 3; dy++) {
#pragma unroll
                for (int dx = 0; dx < 3; dx++) {
                    int rowlin = (pyy + dy) * 10 + (pxx + dx);
                    int sw = rowlin & 7;
                    const unsigned short* tp = tile + rowlin * 64;
                    s8v b0 = *(const s8v*)(tp + (lq ^ sw) * 8);
                    s8v b1v = *(const s8v*)(tp + ((4 + lq) ^ sw) * 8);
                    int t = dy * 3 + dx;
                    acc[n] = __builtin_amdgcn_mfma_f32_16x16x32_bf16(af[t][0], b0, acc[n], 0, 0, 0);
                    acc[n] = __builtin_amdgcn_mfma_f32_16x16x32_bf16(af[t][1], b1v, acc[n], 0, 0, 0);
                }
            }
        }
#pragma unroll
        for (int n = 0; n < 4; n++) {
            int px = n * 16 + l15;
            int sp = (y0 + (px >> 3)) * Wd + x0 + (px & 7);
            alignas(8) unsigned short pk[4];
#pragma unroll
            for (int r = 0; r < 4; r++) pk[r] = f2bf(fmaxf(acc[n][r], 0.f));
            *(uint2*)(ee1h + ibase + (size_t)sp * 64 + co_base + lq * 4) = *(const uint2*)pk;
        }
        return;
    }

    // -------------------------------- gam role
    unsigned short* la = shb;            // 64x128 bf16, 16 KB
    unsigned short* lp = shb + 8192;     // 64x64 bf16, 8 KB
    int p0 = (bid - 512) * 64;
    int b = p0 >> 14;
    int s0 = p0 & (HW - 1);

    const unsigned short* src = gxgyh + (size_t)p0 * 128;
    for (int i = tid; i < 1024; i += 256) {
        int px = i >> 4, cg = i & 15;
        uint4 v = *(const uint4*)(src + px * 128 + cg * 8);
        *(uint4*)(la + px * 128 + ((cg ^ (px & 15)) * 8)) = v;
    }
    int co_base = wv * 16;
    s8v af[4];
#pragma unroll
    for (int h = 0; h < 4; h++)
        af[h] = *(const s8v*)(w1m + (co_base + l15) * 128 + h * 32 + lq * 8);
    f4v bv = *(const f4v*)(b1 + co_base + lq * 4);
    f4v acc[4];
#pragma unroll
    for (int n = 0; n < 4; n++) acc[n] = bv;
    __syncthreads();
#pragma unroll
    for (int n = 0; n < 4; n++) {
        const unsigned short* tp = la + (n * 16 + l15) * 128;
#pragma unroll
        for (int h = 0; h < 4; h++) {
            s8v bb = *(const s8v*)(tp + (((h * 4 + lq) ^ l15) * 8));
            acc[n] = __builtin_amdgcn_mfma_f32_16x16x32_bf16(af[h], bb, acc[n], 0, 0, 0);
        }
    }
    int co = co_base + lq * 4;
    int og = co >> 3;
#pragma unroll
    for (int n = 0; n < 4; n++) {
        int px = n * 16 + l15;
        alignas(8) unsigned short pk[4];
#pragma unroll
        for (int r = 0; r < 4; r++) pk[r] = f2bf(fmaxf(acc[n][r], 0.f));
        *(uint2*)(lp + px * 64 + ((og ^ (px & 7)) * 8) + (co & 7)) = *(const uint2*)pk;
    }
    __syncthreads();
    s8v af2[2];
#pragma unroll
    for (int h = 0; h < 2; h++)
        af2[h] = *(const s8v*)(w2m + l15 * 64 + h * 32 + lq * 8);
    f4v acc2 = *(const f4v*)(b2 + lq * 4);
    int px2 = wv * 16 + l15;
    const unsigned short* tp2 = lp + px2 * 64;
#pragma unroll
    for (int h = 0; h < 2; h++) {
        s8v bb = *(const s8v*)(tp2 + (((h * 4 + lq) ^ (px2 & 7)) * 8));
        acc2 = __builtin_amdgcn_mfma_f32_16x16x32_bf16(af2[h], bb, acc2, 0, 0, 0);
    }
    float* op = ga2 + (size_t)b * 16 * HW + s0 + px2;
#pragma unroll
    for (int r = 0; r < 4; r++)
        op[(lq * 4 + r) * HW] = fmaxf(acc2[r], 0.f);
}

// ---------------------------------------------------------------------------
// K_CD: fused consistency-detector + final 3x3 conv [64][64] MFMA + epilogue.
__global__ __launch_bounds__(256, 2)
void k_CD(const unsigned short* __restrict__ inh,
          const unsigned short* __restrict__ wh,
          const float* __restrict__ bias,
          const float* __restrict__ ga2,
          const float* __restrict__ cd_w1t, const float* __restrict__ cd_b1,
          const float* __restrict__ cd_w2, const float* __restrict__ cd_b2,
          const float* __restrict__ cmPart,
          float* __restrict__ outf,
          const float* __restrict__ x,
          const float* __restrict__ alpha_p) {
    __shared__ unsigned short tile[100 * 64];   // 12.8 KB
    __shared__ float lg[100 * 17];              // 6.8 KB ga2 halo (pad 17)
    __shared__ float lew[64];
    int tid = threadIdx.x;
    int x0 = blockIdx.x * 8, y0 = blockIdx.y * 8;
    int b = blockIdx.z;
    const size_t ibase = (size_t)b * HW * 64;

    for (int i = tid; i < 800; i += 256) {
        int py = i / 80;
        int r = i - py * 80;
        int px = r >> 3, cg = r & 7;
        int gy = y0 - 1 + py, gx = x0 - 1 + px;
        uint4 v = {0u, 0u, 0u, 0u};
        if (gy >= 0 && gy < Hd && gx >= 0 && gx < Wd)
            v = *(const uint4*)(inh + ibase + (size_t)(gy * Wd + gx) * 64 + cg * 8);
        int rowlin = py * 10 + px;
        int scg = cg ^ (rowlin & 7);
        *(uint4*)(tile + rowlin * 64 + scg * 8) = v;
    }
    for (int i = tid; i < 1600; i += 256) {
        int ci = i / 100;
        int r = i - ci * 100;
        int yy = r / 10, xx = r - yy * 10;
        int gy = y0 - 1 + yy, gx = x0 - 1 + xx;
        float v = (gy >= 0 && gy < Hd && gx >= 0 && gx < Wd)
                      ? ga2[((size_t)b * 16 + ci) * HW + gy * Wd + gx] : 0.f;
        lg[r * 17 + ci] = v;
    }

    int lane = tid & 63;
    int wv = tid >> 6;
    int l15 = lane & 15, lq = lane >> 4;
    int co_base = wv * 16;
    s8v af[9][2];
#pragma unroll
    for (int t = 0; t < 9; t++)
#pragma unroll
        for (int h = 0; h < 2; h++)
            af[t][h] = *(const s8v*)(wh + ((t * 64 + co_base + l15) * 64 + h * 32 + lq * 8));
    f4v bv = *(const f4v*)(bias + co_base + lq * 4);
    f4v acc[4];
#pragma unroll
    for (int n = 0; n < 4; n++) acc[n] = bv;
    __syncthreads();

    // ---- ew for pixel (wv*16 + l15), co-quad lq
    {
        int pxl = wv * 16 + l15;            // 0..63
        int py = pxl >> 3, pxx = pxl & 7;
        float ae0 = cd_b1[lq * 4 + 0], ae1 = cd_b1[lq * 4 + 1];
        float ae2 = cd_b1[lq * 4 + 2], ae3 = cd_b1[lq * 4 + 3];
        for (int ci = 0; ci < 16; ci++) {
            float pv[9];
#pragma unroll
            for (int dy = 0; dy < 3; dy++)
#pragma unroll
                for (int dx = 0; dx < 3; dx++)
                    pv[dy * 3 + dx] = lg[((py + dy) * 10 + pxx + dx) * 17 + ci];
            const float* wp = cd_w1t + ci * 144 + lq * 4;
#pragma unroll
            for (int t = 0; t < 9; t++) {
                ae0 = fmaf(pv[t], wp[t * 16 + 0], ae0);
                ae1 = fmaf(pv[t], wp[t * 16 + 1], ae1);
                ae2 = fmaf(pv[t], wp[t * 16 + 2], ae2);
                ae3 = fmaf(pv[t], wp[t * 16 + 3], ae3);
            }
        }
        float ep = fmaxf(ae0, 0.f) * cd_w2[lq * 4 + 0]
                 + fmaxf(ae1, 0.f) * cd_w2[lq * 4 + 1]
                 + fmaxf(ae2, 0.f) * cd_w2[lq * 4 + 2]
                 + fmaxf(ae3, 0.f) * cd_w2[lq * 4 + 3];
        int sp = (y0 + py) * Wd + x0 + pxx;
        float cp = 0.f;
#pragma unroll
        for (int q = 0; q < 4; q++)
            cp += cmPart[(size_t)((b << 4) + lq * 4 + q) * HW + sp];
        ep += __shfl_xor(ep, 16);
        ep += __shfl_xor(ep, 32);
        cp += __shfl_xor(cp, 16);
        cp += __shfl_xor(cp, 32);
        float sig = rcpf(1.f + __expf(-(cd_b2[0] + ep)));
        if (lane < 16) lew[wv * 16 + lane] = sig * cp;
    }
    __syncthreads();

#pragma unroll
    for (int n = 0; n < 4; n++) {
        int px = n * 16 + l15;
        int pyy = px >> 3, pxx = px & 7;
#pragma unroll
        for (int dy = 0; dy < 3; dy++) {
#pragma unroll
            for (int dx = 0; dx < 3; dx++) {
                int rowlin = (pyy + dy) * 10 + (pxx + dx);
                int sw = rowlin & 7;
                const unsigned short* tp = tile + rowlin * 64;
                s8v b0 = *(const s8v*)(tp + (lq ^ sw) * 8);
                s8v b1v = *(const s8v*)(tp + ((4 + lq) ^ sw) * 8);
                int t = dy * 3 + dx;
                acc[n] = __builtin_amdgcn_mfma_f32_16x16x32_bf16(af[t][0], b0, acc[n], 0, 0, 0);
                acc[n] = __builtin_amdgcn_mfma_f32_16x16x32_bf16(af[t][1], b1v, acc[n], 0, 0, 0);
            }
        }
    }
    float alp = alpha_p[0];
#pragma unroll
    for (int n = 0; n < 4; n++) {
        int px = n * 16 + l15;
        int sp = (y0 + (px >> 3)) * Wd + x0 + (px & 7);
        float ae = alp * lew[px];
#pragma unroll
        for (int r = 0; r < 4; r++) {
            size_t o = (size_t)(b * 64 + co_base + lq * 4 + r) * HW + sp;
            outf[o] = fmaf(ae, acc[n][r], x[o]);
        }
    }
}

// ---------------------------------------------------------------------------
extern "C" void kernel_launch(void* const* d_in, const int* in_sizes, int n_in,
                              void* d_out, int out_size, void* d_ws, size_t ws_size,
                              hipStream_t stream) {
    const float* x     = (const float*)d_in[0];
    const float* wgx   = (const float*)d_in[1];
    const float* wgy   = (const float*)d_in[2];
    const float* ga_w1 = (const float*)d_in[3];
    const float* ga_b1 = (const float*)d_in[4];
    const float* ga_w2 = (const float*)d_in[5];
    const float* ga_b2 = (const float*)d_in[6];
    const float* cd_w1 = (const float*)d_in[7];
    const float* cd_b1 = (const float*)d_in[8];
    const float* cd_w2 = (const float*)d_in[9];
    const float* cd_b2 = (const float*)d_in[10];
    const float* ec_w1 = (const float*)d_in[11];
    const float* ec_b1 = (const float*)d_in[12];
    const float* ec_w2 = (const float*)d_in[13];
    const float* ec_b2 = (const float*)d_in[14];
    const float* alpha = (const float*)d_in[15];
    float* out = (float*)d_out;
    float* ws  = (float*)d_ws;

    const size_t N = 2 * 64 * HW;   // 2,097,152 floats

    // buffer plan:
    unsigned short* gxgyh = (unsigned short*)ws;  // 2*HW px * 128ch bf16 = N floats
    float* ga2    = ws + N;                       // 524288 floats
    float* cmPart = ga2 + 2 * 16 * HW;            // 32 slices x HW = 524288 floats
    float* cd_w1t = cmPart + 32 * HW;             // 2304
    unsigned short* w1h = (unsigned short*)(cd_w1t + 2304);  // 36864 shorts
    unsigned short* w2h = w1h + 36864;                       // 36864
    unsigned short* w1m = w2h + 36864;                       // 8192
    unsigned short* w2m = w1m + 8192;                        // 1024
    unsigned short* xh   = (unsigned short*)(ws + 2 * N);    // 2M shorts
    unsigned short* ee1h = xh + N;                           // 2M shorts

    k_A<<<2893, 256, 0, stream>>>(x, wgx, wgy, ga_w1, ga_w2, cd_w1, ec_w1, ec_w2,
                                  gxgyh, cmPart, xh, w1m, w2m, cd_w1t, w1h, w2h);
    k_B<<<1024, 256, 0, stream>>>(xh, w1h, ec_b1, ee1h,
                                  gxgyh, w1m, ga_b1, w2m, ga_b2, ga2);
    k_CD<<<dim3(16, 16, 2), 256, 0, stream>>>(ee1h, w2h, ec_b2, ga2,
                                              cd_w1t, cd_b1, cd_w2, cd_b2,
                                              cmPart, out, x, alpha);
}

// Round 14
// 148.959 us; speedup vs baseline: 1.0220x; 1.0220x over previous
//
#include <hip/hip_runtime.h>
#include <math.h>

#define Hd 128
#define Wd 128
#define HW 16384      // 128*128
#define EPSc 1e-6f

typedef __attribute__((ext_vector_type(8))) short s8v;    // 8 bf16 (4 VGPRs)
typedef __attribute__((ext_vector_type(4))) float f4v;    // 4 fp32

__device__ __forceinline__ unsigned short f2bf(float f) {
    unsigned int u = __float_as_uint(f);
    unsigned int r = (u + 0x7FFFu + ((u >> 16) & 1u)) >> 16;   // RNE
    return (unsigned short)r;
}

__device__ __forceinline__ float rcpf(float x) { return __builtin_amdgcn_rcpf(x); }

// fast atan2, max err ~1e-5 rad (A&S 4.4.49 deg-9 on [0,1] + quadrant fixup)
__device__ __forceinline__ float fatan2(float sy, float sx) {
    float ax = fabsf(sx), ay = fabsf(sy);
    float mx = fmaxf(ax, ay), mn = fminf(ax, ay);
    float q = mn * rcpf(mx);
    float s = q * q;
    float r = q * fmaf(s, fmaf(s, fmaf(s, fmaf(s, 0.0208351f, -0.0851330f),
                                       0.1801410f), -0.3302995f), 0.9998660f);
    if (ay > ax) r = 1.5707963268f - r;
    if (sx < 0.f) r = 3.14159265359f - r;
    r = (sy < 0.f) ? -r : r;
    return (mx == 0.f) ? 0.f : r;
}

// ---------------------------------------------------------------------------
// K_A: 3 roles by blockIdx.x.
//  [0,2048):    sobcons — sobel + 5x5 weighted circular-variance; writes
//               gx/gy as bf16 NHWC[p][128] (LDS-staged -> two 8B coalesced
//               stores per pixel instead of 8x 2B scatter — r13 had 16.8M
//               2-byte scattered global stores chip-wide) and NON-ATOMIC
//               per-quadrant channel-mean partials cmPart[b*16+q][px].
//  [2048,2560): x NCHW fp32 -> xh NHWC bf16 (16 ch/thread).
//  [2560,2893): weight prep (bf16 casts / transposes).
__global__ __launch_bounds__(256, 8)
void k_A(const float* __restrict__ x,
         const float* __restrict__ wgx, const float* __restrict__ wgy,
         const float* __restrict__ ga_w1, const float* __restrict__ ga_w2,
         const float* __restrict__ cd_w1,
         const float* __restrict__ ec_w1, const float* __restrict__ ec_w2,
         unsigned short* __restrict__ gxgyh, float* __restrict__ cmPart,
         unsigned short* __restrict__ xh,
         unsigned short* __restrict__ w1m, unsigned short* __restrict__ w2m,
         float* __restrict__ cd_w1t,
         unsigned short* __restrict__ w1h, unsigned short* __restrict__ w2h) {
    __shared__ float xt[484];              // 22x22 x-tile (3-halo)
    __shared__ float lm[480];              // 20 rows x stride 24
    __shared__ float ld[480];
    __shared__ unsigned short lgxy[2048];  // [pix256][8]: gx c0..3, gy c0..3
    int bid = blockIdx.x;
    int tid = threadIdx.x;

    if (bid < 2048) {                // ---------------- sobcons role
        int bx = bid & 7, by = (bid >> 3) & 7, z = bid >> 6;
        int tx = tid & 15, ty = tid >> 4;
        int x0 = bx * 16, y0 = by * 16;
        int b = z >> 4, cb = (z & 15) * 4;
        float acc = 0.f;
        for (int c = 0; c < 4; c++) {
            int ch = cb + c;
            const float* xp = x + (size_t)(b * 64 + ch) * HW;
            float wx[9], wy[9];
#pragma unroll
            for (int i = 0; i < 9; i++) { wx[i] = wgx[ch * 9 + i]; wy[i] = wgy[ch * 9 + i]; }
            __syncthreads();    // previous channel's cons reads done
            for (int i = tid; i < 484; i += 256) {
                int yy = i / 22, xx = i - yy * 22;
                int gyy = y0 - 3 + yy, gxx = x0 - 3 + xx;
                xt[i] = (gyy >= 0 && gyy < Hd && gxx >= 0 && gxx < Wd) ? xp[gyy * Wd + gxx] : 0.f;
            }
            __syncthreads();
            for (int i = tid; i < 400; i += 256) {
                int yy = i / 20, xx = i - yy * 20;
                int gyy = y0 - 2 + yy, gxx = x0 - 2 + xx;
                float m = 0.f, d = 0.f, sx = 0.f, sy = 0.f;
                if (gyy >= 0 && gyy < Hd && gxx >= 0 && gxx < Wd) {
#pragma unroll
                    for (int dy = 0; dy < 3; dy++)
#pragma unroll
                        for (int dx = 0; dx < 3; dx++) {
                            float v = xt[(yy + dy) * 22 + xx + dx];
                            sx = fmaf(wx[dy * 3 + dx], v, sx);
                            sy = fmaf(wy[dy * 3 + dx], v, sy);
                        }
                    m = sqrtf(sx * sx + sy * sy + EPSc);
                    d = fatan2(sy, sx);
                }
                lm[yy * 24 + xx] = m;
                ld[yy * 24 + xx] = d;
                if (yy >= 2 && yy < 18 && xx >= 2 && xx < 18) {
                    int pix = (yy - 2) * 16 + (xx - 2);
                    lgxy[pix * 8 + c] = f2bf(sx);
                    lgxy[pix * 8 + 4 + c] = f2bf(sy);
                }
            }
            __syncthreads();
            float sm = 0.f, sdm = 0.f, sd2m = 0.f;
#pragma unroll
            for (int r = 0; r < 5; r++)
#pragma unroll
                for (int cx = 0; cx < 5; cx++) {
                    int idx = (ty + r) * 24 + tx + cx;
                    float m = lm[idx], d = ld[idx];
                    sm += m;
                    float dm = d * m;
                    sdm += dm;
                    sd2m = fmaf(d, dm, sd2m);
                }
            float rinv = rcpf(sm + EPSc);
            float w = sdm * rinv;
            float sv = fmaf(w, fmaf(w, sm, -2.f * sdm), sd2m);  // sd2m - 2w*sdm + w^2*sm
            sv = fmaxf(sv, 0.f);
            float wstd = sqrtf(sv * rinv);
            acc += 2.f * rcpf(__expf(2.f * wstd) + 1.f);   // = 1 - tanh(wstd)
        }
        int sp = (y0 + ty) * Wd + x0 + tx;
        cmPart[(size_t)z * HW + sp] = acc * (1.f / 64.f);
        // coalesced gx/gy flush: two 8B stores per pixel (4ch gx, 4ch gy)
        {
            int pix = ty * 16 + tx;
            size_t pb = ((size_t)b * HW + sp) * 128;
            const uint2* s2 = (const uint2*)(lgxy + pix * 8);
            *(uint2*)(gxgyh + pb + cb) = s2[0];
            *(uint2*)(gxgyh + pb + 64 + cb) = s2[1];
        }
        return;
    }
    if (bid < 2560) {                // ---------------- xh role (16 ch/thread)
        int idx = (bid - 2048) * 256 + tid;    // [0, 131072)
        int cg = idx >> 15;                    // 16-ch group 0..3
        int p  = idx & 32767;
        int b = p >> 14, s = p & (HW - 1);
        const float* xp = x + ((size_t)b * 64 + cg * 16) * HW + s;
        alignas(16) unsigned short buf[16];
#pragma unroll
        for (int k = 0; k < 16; k++) buf[k] = f2bf(xp[k * HW]);
        uint4* dst = (uint4*)(xh + (size_t)p * 64 + cg * 16);
        dst[0] = ((const uint4*)buf)[0];
        dst[1] = ((const uint4*)buf)[1];
        return;
    }
    int i = (bid - 2560) * 256 + tid;          // ------- weight prep
    if (i < 36864) {                               // w1h [t][co][ci] bf16 (ec_w1)
        int t = i >> 12, co = (i >> 6) & 63, ci = i & 63;
        w1h[i] = f2bf(ec_w1[(co * 64 + ci) * 9 + t]);
    } else if (i < 73728) {                        // w2h (ec_w2)
        int j = i - 36864;
        int t = j >> 12, co = (j >> 6) & 63, ci = j & 63;
        w2h[j] = f2bf(ec_w2[(co * 64 + ci) * 9 + t]);
    } else if (i < 81920) {                        // w1m [co64][K128] = ga_w1 cast
        int j = i - 73728;
        w1m[j] = f2bf(ga_w1[j]);
    } else if (i < 82944) {                        // w2m [co16][ci64] = ga_w2 cast
        int j = i - 81920;
        w2m[j] = f2bf(ga_w2[j]);
    } else if (i < 85248) {                        // cd_w1t [ci16][tap9][co16] fp32
        int j = i - 82944;
        int co = j & 15, r = j >> 4, t = r % 9, ci = r / 9;
        cd_w1t[j] = cd_w1[(co * 16 + ci) * 9 + t];
    }
}

// ---------------------------------------------------------------------------
// K_B: 2 roles by blockIdx.x (LDS union 24 KB).
//  [0,512):    conv64 stage-1 (3x3 64->64 MFMA, relu -> bf16 NHWC ee1h)
//  [512,1024): gam — ga1+ga2 fused MFMA GEMM -> ga2 fp32 NCHW
__global__ __launch_bounds__(256, 2)
void k_B(const unsigned short* __restrict__ xh,
         const unsigned short* __restrict__ w1h, const float* __restrict__ ec_b1,
         unsigned short* __restrict__ ee1h,
         const unsigned short* __restrict__ gxgyh,
         const unsigned short* __restrict__ w1m, const float* __restrict__ b1,
         const unsigned short* __restrict__ w2m, const float* __restrict__ b2,
         float* __restrict__ ga2) {
    __shared__ unsigned short shb[12288];   // 24 KB union
    int bid = blockIdx.x;
    int tid = threadIdx.x;
    int lane = tid & 63, wv = tid >> 6;
    int l15 = lane & 15, lq = lane >> 4;

    if (bid < 512) {                 // ---------------- conv64 stage-1 role
        unsigned short* tile = shb;  // 100x64 bf16, 12.8 KB
        int j = bid;
        int x0 = (j & 15) * 8, y0 = ((j >> 4) & 15) * 8;
        int b = j >> 8;
        const size_t ibase = (size_t)b * HW * 64;

        for (int i = tid; i < 800; i += 256) {
            int py = i / 80;
            int r = i - py * 80;
            int px = r >> 3, cg = r & 7;
            int gy = y0 - 1 + py, gx = x0 - 1 + px;
            uint4 v = {0u, 0u, 0u, 0u};
            if (gy >= 0 && gy < Hd && gx >= 0 && gx < Wd)
                v = *(const uint4*)(xh + ibase + (size_t)(gy * Wd + gx) * 64 + cg * 8);
            int rowlin = py * 10 + px;
            int scg = cg ^ (rowlin & 7);
            *(uint4*)(tile + rowlin * 64 + scg * 8) = v;
        }
        int co_base = wv * 16;
        s8v af[9][2];
#pragma unroll
        for (int t = 0; t < 9; t++)
#pragma unroll
            for (int h = 0; h < 2; h++)
                af[t][h] = *(const s8v*)(w1h + ((t * 64 + co_base + l15) * 64 + h * 32 + lq * 8));
        f4v bv = *(const f4v*)(ec_b1 + co_base + lq * 4);
        f4v acc[4];
#pragma unroll
        for (int n = 0; n < 4; n++) acc[n] = bv;
        __syncthreads();
#pragma unroll
        for (int n = 0; n < 4; n++) {
            int px = n * 16 + l15;
            int pyy = px >> 3, pxx = px & 7;
#pragma unroll
            for (int dy = 0; dy < 3; dy++) {
#pragma unroll
                for (int dx = 0; dx < 3; dx++) {
                    int rowlin = (pyy + dy) * 10 + (pxx + dx);
                    int sw = rowlin & 7;
                    const unsigned short* tp = tile + rowlin * 64;
                    s8v b0 = *(const s8v*)(tp + (lq ^ sw) * 8);
                    s8v b1v = *(const s8v*)(tp + ((4 + lq) ^ sw) * 8);
                    int t = dy * 3 + dx;
                    acc[n] = __builtin_amdgcn_mfma_f32_16x16x32_bf16(af[t][0], b0, acc[n], 0, 0, 0);
                    acc[n] = __builtin_amdgcn_mfma_f32_16x16x32_bf16(af[t][1], b1v, acc[n], 0, 0, 0);
                }
            }
        }
#pragma unroll
        for (int n = 0; n < 4; n++) {
            int px = n * 16 + l15;
            int sp = (y0 + (px >> 3)) * Wd + x0 + (px & 7);
            alignas(8) unsigned short pk[4];
#pragma unroll
            for (int r = 0; r < 4; r++) pk[r] = f2bf(fmaxf(acc[n][r], 0.f));
            *(uint2*)(ee1h + ibase + (size_t)sp * 64 + co_base + lq * 4) = *(const uint2*)pk;
        }
        return;
    }

    // -------------------------------- gam role
    unsigned short* la = shb;            // 64x128 bf16, 16 KB
    unsigned short* lp = shb + 8192;     // 64x64 bf16, 8 KB
    int p0 = (bid - 512) * 64;
    int b = p0 >> 14;
    int s0 = p0 & (HW - 1);

    const unsigned short* src = gxgyh + (size_t)p0 * 128;
    for (int i = tid; i < 1024; i += 256) {
        int px = i >> 4, cg = i & 15;
        uint4 v = *(const uint4*)(src + px * 128 + cg * 8);
        *(uint4*)(la + px * 128 + ((cg ^ (px & 15)) * 8)) = v;
    }
    int co_base = wv * 16;
    s8v af[4];
#pragma unroll
    for (int h = 0; h < 4; h++)
        af[h] = *(const s8v*)(w1m + (co_base + l15) * 128 + h * 32 + lq * 8);
    f4v bv = *(const f4v*)(b1 + co_base + lq * 4);
    f4v acc[4];
#pragma unroll
    for (int n = 0; n < 4; n++) acc[n] = bv;
    __syncthreads();
#pragma unroll
    for (int n = 0; n < 4; n++) {
        const unsigned short* tp = la + (n * 16 + l15) * 128;
#pragma unroll
        for (int h = 0; h < 4; h++) {
            s8v bb = *(const s8v*)(tp + (((h * 4 + lq) ^ l15) * 8));
            acc[n] = __builtin_amdgcn_mfma_f32_16x16x32_bf16(af[h], bb, acc[n], 0, 0, 0);
        }
    }
    int co = co_base + lq * 4;
    int og = co >> 3;
#pragma unroll
    for (int n = 0; n < 4; n++) {
        int px = n * 16 + l15;
        alignas(8) unsigned short pk[4];
#pragma unroll
        for (int r = 0; r < 4; r++) pk[r] = f2bf(fmaxf(acc[n][r], 0.f));
        *(uint2*)(lp + px * 64 + ((og ^ (px & 7)) * 8) + (co & 7)) = *(const uint2*)pk;
    }
    __syncthreads();
    s8v af2[2];
#pragma unroll
    for (int h = 0; h < 2; h++)
        af2[h] = *(const s8v*)(w2m + l15 * 64 + h * 32 + lq * 8);
    f4v acc2 = *(const f4v*)(b2 + lq * 4);
    int px2 = wv * 16 + l15;
    const unsigned short* tp2 = lp + px2 * 64;
#pragma unroll
    for (int h = 0; h < 2; h++) {
        s8v bb = *(const s8v*)(tp2 + (((h * 4 + lq) ^ (px2 & 7)) * 8));
        acc2 = __builtin_amdgcn_mfma_f32_16x16x32_bf16(af2[h], bb, acc2, 0, 0, 0);
    }
    float* op = ga2 + (size_t)b * 16 * HW + s0 + px2;
#pragma unroll
    for (int r = 0; r < 4; r++)
        op[(lq * 4 + r) * HW] = fmaxf(acc2[r], 0.f);
}

// ---------------------------------------------------------------------------
// K_CD: fused consistency-detector + final 3x3 conv [64][64] MFMA + epilogue.
__global__ __launch_bounds__(256, 2)
void k_CD(const unsigned short* __restrict__ inh,
          const unsigned short* __restrict__ wh,
          const float* __restrict__ bias,
          const float* __restrict__ ga2,
          const float* __restrict__ cd_w1t, const float* __restrict__ cd_b1,
          const float* __restrict__ cd_w2, const float* __restrict__ cd_b2,
          const float* __restrict__ cmPart,
          float* __restrict__ outf,
          const float* __restrict__ x,
          const float* __restrict__ alpha_p) {
    __shared__ unsigned short tile[100 * 64];   // 12.8 KB
    __shared__ float lg[100 * 17];              // 6.8 KB ga2 halo (pad 17)
    __shared__ float lew[64];
    int tid = threadIdx.x;
    int x0 = blockIdx.x * 8, y0 = blockIdx.y * 8;
    int b = blockIdx.z;
    const size_t ibase = (size_t)b * HW * 64;

    for (int i = tid; i < 800; i += 256) {
        int py = i / 80;
        int r = i - py * 80;
        int px = r >> 3, cg = r & 7;
        int gy = y0 - 1 + py, gx = x0 - 1 + px;
        uint4 v = {0u, 0u, 0u, 0u};
        if (gy >= 0 && gy < Hd && gx >= 0 && gx < Wd)
            v = *(const uint4*)(inh + ibase + (size_t)(gy * Wd + gx) * 64 + cg * 8);
        int rowlin = py * 10 + px;
        int scg = cg ^ (rowlin & 7);
        *(uint4*)(tile + rowlin * 64 + scg * 8) = v;
    }
    for (int i = tid; i < 1600; i += 256) {
        int ci = i / 100;
        int r = i - ci * 100;
        int yy = r / 10, xx = r - yy * 10;
        int gy = y0 - 1 + yy, gx = x0 - 1 + xx;
        float v = (gy >= 0 && gy < Hd && gx >= 0 && gx < Wd)
                      ? ga2[((size_t)b * 16 + ci) * HW + gy * Wd + gx] : 0.f;
        lg[r * 17 + ci] = v;
    }

    int lane = tid & 63;
    int wv = tid >> 6;
    int l15 = lane & 15, lq = lane >> 4;
    int co_base = wv * 16;
    s8v af[9][2];
#pragma unroll
    for (int t = 0; t < 9; t++)
#pragma unroll
        for (int h = 0; h < 2; h++)
            af[t][h] = *(const s8v*)(wh + ((t * 64 + co_base + l15) * 64 + h * 32 + lq * 8));
    f4v bv = *(const f4v*)(bias + co_base + lq * 4);
    f4v acc[4];
#pragma unroll
    for (int n = 0; n < 4; n++) acc[n] = bv;
    __syncthreads();

    // ---- ew for pixel (wv*16 + l15), co-quad lq
    {
        int pxl = wv * 16 + l15;            // 0..63
        int py = pxl >> 3, pxx = pxl & 7;
        float ae0 = cd_b1[lq * 4 + 0], ae1 = cd_b1[lq * 4 + 1];
        float ae2 = cd_b1[lq * 4 + 2], ae3 = cd_b1[lq * 4 + 3];
        for (int ci = 0; ci < 16; ci++) {
            float pv[9];
#pragma unroll
            for (int dy = 0; dy < 3; dy++)
#pragma unroll
                for (int dx = 0; dx < 3; dx++)
                    pv[dy * 3 + dx] = lg[((py + dy) * 10 + pxx + dx) * 17 + ci];
            const float* wp = cd_w1t + ci * 144 + lq * 4;
#pragma unroll
            for (int t = 0; t < 9; t++) {
                ae0 = fmaf(pv[t], wp[t * 16 + 0], ae0);
                ae1 = fmaf(pv[t], wp[t * 16 + 1], ae1);
                ae2 = fmaf(pv[t], wp[t * 16 + 2], ae2);
                ae3 = fmaf(pv[t], wp[t * 16 + 3], ae3);
            }
        }
        float ep = fmaxf(ae0, 0.f) * cd_w2[lq * 4 + 0]
                 + fmaxf(ae1, 0.f) * cd_w2[lq * 4 + 1]
                 + fmaxf(ae2, 0.f) * cd_w2[lq * 4 + 2]
                 + fmaxf(ae3, 0.f) * cd_w2[lq * 4 + 3];
        int sp = (y0 + py) * Wd + x0 + pxx;
        float cp = 0.f;
#pragma unroll
        for (int q = 0; q < 4; q++)
            cp += cmPart[(size_t)((b << 4) + lq * 4 + q) * HW + sp];
        ep += __shfl_xor(ep, 16);
        ep += __shfl_xor(ep, 32);
        cp += __shfl_xor(cp, 16);
        cp += __shfl_xor(cp, 32);
        float sig = rcpf(1.f + __expf(-(cd_b2[0] + ep)));
        if (lane < 16) lew[wv * 16 + lane] = sig * cp;
    }
    __syncthreads();

#pragma unroll
    for (int n = 0; n < 4; n++) {
        int px = n * 16 + l15;
        int pyy = px >> 3, pxx = px & 7;
#pragma unroll
        for (int dy = 0; dy < 3; dy++) {
#pragma unroll
            for (int dx = 0; dx < 3; dx++) {
                int rowlin = (pyy + dy) * 10 + (pxx + dx);
                int sw = rowlin & 7;
                const unsigned short* tp = tile + rowlin * 64;
                s8v b0 = *(const s8v*)(tp + (lq ^ sw) * 8);
                s8v b1v = *(const s8v*)(tp + ((4 + lq) ^ sw) * 8);
                int t = dy * 3 + dx;
                acc[n] = __builtin_amdgcn_mfma_f32_16x16x32_bf16(af[t][0], b0, acc[n], 0, 0, 0);
                acc[n] = __builtin_amdgcn_mfma_f32_16x16x32_bf16(af[t][1], b1v, acc[n], 0, 0, 0);
            }
        }
    }
    float alp = alpha_p[0];
#pragma unroll
    for (int n = 0; n < 4; n++) {
        int px = n * 16 + l15;
        int sp = (y0 + (px >> 3)) * Wd + x0 + (px & 7);
        float ae = alp * lew[px];
#pragma unroll
        for (int r = 0; r < 4; r++) {
            size_t o = (size_t)(b * 64 + co_base + lq * 4 + r) * HW + sp;
            outf[o] = fmaf(ae, acc[n][r], x[o]);
        }
    }
}

// ---------------------------------------------------------------------------
extern "C" void kernel_launch(void* const* d_in, const int* in_sizes, int n_in,
                              void* d_out, int out_size, void* d_ws, size_t ws_size,
                              hipStream_t stream) {
    const float* x     = (const float*)d_in[0];
    const float* wgx   = (const float*)d_in[1];
    const float* wgy   = (const float*)d_in[2];
    const float* ga_w1 = (const float*)d_in[3];
    const float* ga_b1 = (const float*)d_in[4];
    const float* ga_w2 = (const float*)d_in[5];
    const float* ga_b2 = (const float*)d_in[6];
    const float* cd_w1 = (const float*)d_in[7];
    const float* cd_b1 = (const float*)d_in[8];
    const float* cd_w2 = (const float*)d_in[9];
    const float* cd_b2 = (const float*)d_in[10];
    const float* ec_w1 = (const float*)d_in[11];
    const float* ec_b1 = (const float*)d_in[12];
    const float* ec_w2 = (const float*)d_in[13];
    const float* ec_b2 = (const float*)d_in[14];
    const float* alpha = (const float*)d_in[15];
    float* out = (float*)d_out;
    float* ws  = (float*)d_ws;

    const size_t N = 2 * 64 * HW;   // 2,097,152 floats

    // buffer plan:
    unsigned short* gxgyh = (unsigned short*)ws;  // 2*HW px * 128ch bf16 = N floats
    float* ga2    = ws + N;                       // 524288 floats
    float* cmPart = ga2 + 2 * 16 * HW;            // 32 slices x HW = 524288 floats
    float* cd_w1t = cmPart + 32 * HW;             // 2304
    unsigned short* w1h = (unsigned short*)(cd_w1t + 2304);  // 36864 shorts
    unsigned short* w2h = w1h + 36864;                       // 36864
    unsigned short* w1m = w2h + 36864;                       // 8192
    unsigned short* w2m = w1m + 8192;                        // 1024
    unsigned short* xh   = (unsigned short*)(ws + 2 * N);    // 2M shorts
    unsigned short* ee1h = xh + N;                           // 2M shorts

    k_A<<<2893, 256, 0, stream>>>(x, wgx, wgy, ga_w1, ga_w2, cd_w1, ec_w1, ec_w2,
                                  gxgyh, cmPart, xh, w1m, w2m, cd_w1t, w1h, w2h);
    k_B<<<1024, 256, 0, stream>>>(xh, w1h, ec_b1, ee1h,
                                  gxgyh, w1m, ga_b1, w2m, ga_b2, ga2);
    k_CD<<<dim3(16, 16, 2), 256, 0, stream>>>(ee1h, w2h, ec_b2, ga2,
                                              cd_w1t, cd_b1, cd_w2, cd_b2,
                                              cmPart, out, x, alpha);
}